// Round 2
// baseline (3256.372 us; speedup 1.0000x reference)
//
#include <hip/hip_runtime.h>

// ---------------- problem geometry ----------------
#define BB   4
#define LL   2048
#define CC   1024
#define SEG  8                      // timesteps held in registers per thread
#define NSEG (LL / SEG)             // 256 segments per chain
#define CBLK 256                    // channels per block
#define CG   (CC / CBLK)            // 4 channel-groups
#define NT   (BB * NSEG * CG)       // 4096 tiles (blocks), power of two
#define CHAIN_STRIDE (BB * CG)      // 16: tile distance between s and s+1, same (b,cg)
#define POLL_CAP 32768              // spin cap before self-compute fallback

// ---------------- workspace layout (bytes) ----------------
// [0,4)            tile counter
// [128, 128+4*NT)  flags: 0=empty 1=aggregate 2=inclusive
// [32768, +64MiB)  aggregate payloads [tile][k=0..7][CBLK] as u64 (2 floats)
// [..,    +64MiB)  inclusive payloads, same layout
#define FLAG_OFF   128
#define CTRL_BYTES 32768
#define PAY_U64_PER_TILE (8 * CBLK)

typedef unsigned long long u64;
typedef float f32x4 __attribute__((ext_vector_type(4)));

struct Cplx { float r, i; };

__device__ __forceinline__ Cplx cmul(Cplx a, Cplx b) {
    Cplx o;
    o.r = fmaf(a.r, b.r, -a.i * b.i);
    o.i = fmaf(a.r, b.i,  a.i * b.r);
    return o;
}
__device__ __forceinline__ Cplx cfma(Cplx a, Cplx b, Cplx acc) {
    acc.r = fmaf(a.r, b.r, fmaf(-a.i, b.i, acc.r));
    acc.i = fmaf(a.r, b.i, fmaf( a.i, b.r, acc.i));
    return acc;
}

// Nontemporal 2x2 complex load/store (A,X,out are zero-reuse streams).
__device__ __forceinline__ void load_mat_nt(const float* __restrict__ p, Cplx m[4]) {
    const f32x4* p4 = (const f32x4*)p;
    f32x4 v0 = __builtin_nontemporal_load(p4);
    f32x4 v1 = __builtin_nontemporal_load(p4 + 1);
    m[0].r = v0.x; m[0].i = v0.y;
    m[1].r = v0.z; m[1].i = v0.w;
    m[2].r = v1.x; m[2].i = v1.y;
    m[3].r = v1.z; m[3].i = v1.w;
}
__device__ __forceinline__ void store_mat_nt(float* __restrict__ p, const Cplx m[4]) {
    f32x4* p4 = (f32x4*)p;
    f32x4 v0 = {m[0].r, m[0].i, m[1].r, m[1].i};
    f32x4 v1 = {m[2].r, m[2].i, m[3].r, m[3].i};
    __builtin_nontemporal_store(v0, p4);
    __builtin_nontemporal_store(v1, p4 + 1);
}

// out = a @ m   (2x2 complex)
__device__ __forceinline__ void matmul(const Cplx a[4], const Cplx m[4], Cplx out[4]) {
    #pragma unroll
    for (int ik = 0; ik < 4; ++ik) {
        int i = ik >> 1, k = ik & 1;
        Cplx t = cmul(a[i * 2 + 0], m[0 * 2 + k]);
        out[ik] = cfma(a[i * 2 + 1], m[1 * 2 + k], t);
    }
}
// out = a @ m + x
__device__ __forceinline__ void matmul_add(const Cplx a[4], const Cplx m[4],
                                           const Cplx x[4], Cplx out[4]) {
    #pragma unroll
    for (int ik = 0; ik < 4; ++ik) {
        int i = ik >> 1, k = ik & 1;
        Cplx t = cfma(a[i * 2 + 0], m[0 * 2 + k], x[ik]);
        out[ik] = cfma(a[i * 2 + 1], m[1 * 2 + k], t);
    }
}

__device__ __forceinline__ u64 pack2(float lo, float hi) {
    return (u64)__float_as_uint(lo) | ((u64)__float_as_uint(hi) << 32);
}
__device__ __forceinline__ void unpack2(u64 v, float& lo, float& hi) {
    lo = __uint_as_float((unsigned)v);
    hi = __uint_as_float((unsigned)(v >> 32));
}

// Cross-XCD payloads: agent-scope atomics; plane-major [k][CBLK] layout so each
// instruction is lane-contiguous (2 KiB per plane per block).
__device__ __forceinline__ void payload_store(u64* base, int tid,
                                              const Cplx Am[4], const Cplx Xm[4]) {
    #pragma unroll
    for (int k = 0; k < 4; ++k)
        __hip_atomic_store(base + (size_t)k * CBLK + tid, pack2(Am[k].r, Am[k].i),
                           __ATOMIC_RELAXED, __HIP_MEMORY_SCOPE_AGENT);
    #pragma unroll
    for (int k = 0; k < 4; ++k)
        __hip_atomic_store(base + (size_t)(4 + k) * CBLK + tid, pack2(Xm[k].r, Xm[k].i),
                           __ATOMIC_RELAXED, __HIP_MEMORY_SCOPE_AGENT);
}
__device__ __forceinline__ void payload_load(const u64* base, int tid,
                                             Cplx Am[4], Cplx Xm[4]) {
    u64* b = (u64*)base;
    #pragma unroll
    for (int k = 0; k < 4; ++k) {
        u64 v = __hip_atomic_load(b + (size_t)k * CBLK + tid,
                                  __ATOMIC_RELAXED, __HIP_MEMORY_SCOPE_AGENT);
        unpack2(v, Am[k].r, Am[k].i);
    }
    #pragma unroll
    for (int k = 0; k < 4; ++k) {
        u64 v = __hip_atomic_load(b + (size_t)(4 + k) * CBLK + tid,
                                  __ATOMIC_RELAXED, __HIP_MEMORY_SCOPE_AGENT);
        unpack2(v, Xm[k].r, Xm[k].i);
    }
}

__global__ __launch_bounds__(256, 2)
void pscan_lookback(const float* __restrict__ A, const float* __restrict__ X,
                    unsigned char* __restrict__ wsb, float* __restrict__ out) {
    unsigned* counter = (unsigned*)wsb;
    unsigned* flags   = (unsigned*)(wsb + FLAG_OFF);
    u64* agg = (u64*)(wsb + CTRL_BYTES);
    u64* inc = agg + (size_t)NT * PAY_U64_PER_TILE;

    // Ordered tile assignment: a block only waits on tiles whose owners already
    // executed atomicAdd (i.e. are resident and independent of later tickets).
    // Mask to NT-1 so even an un-reset counter can never index out of bounds.
    __shared__ unsigned s_tile;
    const int tid = threadIdx.x;
    if (tid == 0) s_tile = atomicAdd(counter, 1u) & (unsigned)(NT - 1);
    __syncthreads();
    const unsigned tile = s_tile;

    const int cg = tile % CG;
    const int b  = (tile / CG) % BB;
    const int s  = tile / (CG * BB);        // slowest-varying: predecessors ticketed first
    const int c  = cg * CBLK + tid;

    const long base = (((long)b * LL + (long)s * SEG) * CC + c) * 8;
    const long step = (long)CC * 8;

    // ---- phase 1: read segment once (nontemporal); build within-segment
    //      inclusive transforms (Pa_t, Px_t) fully in registers (static indices).
    Cplx Pa[SEG][4], Px[SEG][4];
    load_mat_nt(A + base, Pa[0]);
    load_mat_nt(X + base, Px[0]);
    #pragma unroll
    for (int t = 1; t < SEG; ++t) {
        Cplx a[4], x[4];
        long p = base + (long)t * step;
        load_mat_nt(A + p, a);
        load_mat_nt(X + p, x);
        matmul(a, Pa[t - 1], Pa[t]);               // Pa_t = A_t @ Pa_{t-1}
        matmul_add(a, Px[t - 1], x, Px[t]);        // Px_t = A_t @ Px_{t-1} + X_t
    }

    u64* myagg = agg + (size_t)tile * PAY_U64_PER_TILE;
    u64* myinc = inc + (size_t)tile * PAY_U64_PER_TILE;
    const bool has_succ = (s != NSEG - 1);

    // ---- publish aggregate early (decoupled lookback)
    if (s > 0 && has_succ) {
        payload_store(myagg, tid, Pa[SEG - 1], Px[SEG - 1]);
        __threadfence();                            // each thread releases its stores
        __syncthreads();
        if (tid == 0)
            __hip_atomic_store(&flags[tile], 1u, __ATOMIC_RELEASE, __HIP_MEMORY_SCOPE_AGENT);
    }

    // ---- lookback: acc = T_{s-1} o ... o T_0
    Cplx accA[4], accX[4];
    accA[0] = {1.f, 0.f}; accA[1] = {0.f, 0.f};
    accA[2] = {0.f, 0.f}; accA[3] = {1.f, 0.f};
    #pragma unroll
    for (int k = 0; k < 4; ++k) accX[k] = {0.f, 0.f};

    if (s > 0) {
        int j = (int)tile - CHAIN_STRIDE;
        for (;;) {
            unsigned f = __hip_atomic_load(&flags[j], __ATOMIC_RELAXED,
                                           __HIP_MEMORY_SCOPE_AGENT);
            int polls = 0;
            while (f == 0u && polls < POLL_CAP) {
                __builtin_amdgcn_s_sleep(2);
                f = __hip_atomic_load(&flags[j], __ATOMIC_RELAXED,
                                      __HIP_MEMORY_SCOPE_AGENT);
                ++polls;
            }

            if (f != 0u) {
                __builtin_amdgcn_fence(__ATOMIC_ACQUIRE, "agent");
                const u64* src = ((f == 2u) ? inc : agg) + (size_t)j * PAY_U64_PER_TILE;
                Cplx Ja[4], Jx[4];
                payload_load(src, tid, Ja, Jx);

                Cplx tA[4], tX[4];
                matmul(accA, Ja, tA);               // acc = acc o T_j
                matmul_add(accA, Jx, accX, tX);
                #pragma unroll
                for (int k = 0; k < 4; ++k) { accA[k] = tA[k]; accX[k] = tX[k]; }

                if (f == 2u) break;                 // folded an inclusive prefix: done
                j -= CHAIN_STRIDE;
            } else {
                // Timed out: self-compute T_j from A,X (exact same values the
                // owner would publish). Guarantees termination unconditionally.
                int sj = j / CHAIN_STRIDE;          // same (b,cg) as us
                long jb = (((long)b * LL + (long)sj * SEG) * CC + c) * 8;
                Cplx Ja[4], Jx[4];
                load_mat_nt(A + jb, Ja);
                load_mat_nt(X + jb, Jx);
                for (int t = 1; t < SEG; ++t) {
                    Cplx a2[4], x2[4], nA[4], nX[4];
                    long p = jb + (long)t * step;
                    load_mat_nt(A + p, a2);
                    load_mat_nt(X + p, x2);
                    matmul(a2, Ja, nA);
                    matmul_add(a2, Jx, x2, nX);
                    #pragma unroll
                    for (int k = 0; k < 4; ++k) { Ja[k] = nA[k]; Jx[k] = nX[k]; }
                }
                Cplx tA[4], tX[4];
                matmul(accA, Ja, tA);
                matmul_add(accA, Jx, accX, tX);
                #pragma unroll
                for (int k = 0; k < 4; ++k) { accA[k] = tA[k]; accX[k] = tX[k]; }

                if (sj == 0) break;                 // reached chain start
                j -= CHAIN_STRIDE;
            }
        }
    }

    // ---- publish inclusive prefix (T_s o acc) for successors
    if (has_succ) {
        Cplx Ia[4], Ix[4];
        if (s > 0) {
            matmul(Pa[SEG - 1], accA, Ia);
            matmul_add(Pa[SEG - 1], accX, Px[SEG - 1], Ix);
        } else {
            #pragma unroll
            for (int k = 0; k < 4; ++k) { Ia[k] = Pa[SEG - 1][k]; Ix[k] = Px[SEG - 1][k]; }
        }
        payload_store(myinc, tid, Ia, Ix);
        __threadfence();
        __syncthreads();
        if (tid == 0)
            __hip_atomic_store(&flags[tile], 2u, __ATOMIC_RELEASE, __HIP_MEMORY_SCOPE_AGENT);
    }

    // ---- finalize from registers: Y_t = Pa_t @ Y_in + Px_t, Y_in = accX
    #pragma unroll
    for (int t = 0; t < SEG; ++t) {
        Cplx Y[4];
        matmul_add(Pa[t], accX, Px[t], Y);
        store_mat_nt(out + base + (long)t * step, Y);
    }
}

extern "C" void kernel_launch(void* const* d_in, const int* in_sizes, int n_in,
                              void* d_out, int out_size, void* d_ws, size_t ws_size,
                              hipStream_t stream) {
    const float* A = (const float*)d_in[0];
    const float* X = (const float*)d_in[1];

    // zero counter + flags only (payloads are flag-gated; they are also pure
    // functions of the constant inputs, so even stale payloads are correct)
    hipMemsetAsync(d_ws, 0, CTRL_BYTES, stream);
    pscan_lookback<<<NT, dim3(256), 0, stream>>>(A, X, (unsigned char*)d_ws, (float*)d_out);
}

// Round 3
// 2675.389 us; speedup vs baseline: 1.2172x; 1.2172x over previous
//
#include <hip/hip_runtime.h>

// ---------------- problem geometry ----------------
#define BB   4
#define LL   2048
#define CC   1024
#define SEG  8                       // timesteps per thread (registers)
#define TCH  32                      // channels per tile
#define TSS  8                       // sub-segments per tile (threads per channel)
#define TSPAN (SEG * TSS)            // 64 timesteps per tile
#define NCG  (CC / TCH)              // 32 channel-groups
#define NCHAIN (BB * NCG)            // 128 independent chains
#define NPOS (LL / TSPAN)            // 32 positions per chain
#define NT   (NCHAIN * NPOS)         // 4096 tiles
#define NBLK 1024                    // persistent worker blocks
#define POLL_CAP 8192

// ---------------- workspace layout (bytes) ----------------
// [0,4)        ticket counter
// [128, +16KB) flags[NT]: 0=empty 1=aggregate ready 2=carry ready
// [32768, +8MB)  agg payloads: [tile][plane 0..7][TCH] u64 (A:0-3, X:4-7)
// [.., +4MB)     carry payloads: [tile][plane 0..3][TCH] u64 (state Y)
#define FLAG_OFF   128
#define CTRL_BYTES 32768
#define AGG_U64_PER_TILE (8 * TCH)
#define CAR_U64_PER_TILE (4 * TCH)

typedef unsigned long long u64;
typedef float f32x4 __attribute__((ext_vector_type(4)));

struct Cplx { float r, i; };

__device__ __forceinline__ Cplx cmul(Cplx a, Cplx b) {
    Cplx o;
    o.r = fmaf(a.r, b.r, -a.i * b.i);
    o.i = fmaf(a.r, b.i,  a.i * b.r);
    return o;
}
__device__ __forceinline__ Cplx cfma(Cplx a, Cplx b, Cplx acc) {
    acc.r = fmaf(a.r, b.r, fmaf(-a.i, b.i, acc.r));
    acc.i = fmaf(a.r, b.i, fmaf( a.i, b.r, acc.i));
    return acc;
}

__device__ __forceinline__ void load_mat_nt(const float* __restrict__ p, Cplx m[4]) {
    const f32x4* p4 = (const f32x4*)p;
    f32x4 v0 = __builtin_nontemporal_load(p4);
    f32x4 v1 = __builtin_nontemporal_load(p4 + 1);
    m[0].r = v0.x; m[0].i = v0.y;
    m[1].r = v0.z; m[1].i = v0.w;
    m[2].r = v1.x; m[2].i = v1.y;
    m[3].r = v1.z; m[3].i = v1.w;
}
__device__ __forceinline__ void store_mat_nt(float* __restrict__ p, const Cplx m[4]) {
    f32x4* p4 = (f32x4*)p;
    f32x4 v0 = {m[0].r, m[0].i, m[1].r, m[1].i};
    f32x4 v1 = {m[2].r, m[2].i, m[3].r, m[3].i};
    __builtin_nontemporal_store(v0, p4);
    __builtin_nontemporal_store(v1, p4 + 1);
}

// out = a @ m (2x2 complex)
__device__ __forceinline__ void matmul(const Cplx a[4], const Cplx m[4], Cplx out[4]) {
    #pragma unroll
    for (int ik = 0; ik < 4; ++ik) {
        int i = ik >> 1, k = ik & 1;
        Cplx t = cmul(a[i * 2 + 0], m[0 * 2 + k]);
        out[ik] = cfma(a[i * 2 + 1], m[1 * 2 + k], t);
    }
}
// out = a @ m + x
__device__ __forceinline__ void matmul_add(const Cplx a[4], const Cplx m[4],
                                           const Cplx x[4], Cplx out[4]) {
    #pragma unroll
    for (int ik = 0; ik < 4; ++ik) {
        int i = ik >> 1, k = ik & 1;
        Cplx t = cfma(a[i * 2 + 0], m[0 * 2 + k], x[ik]);
        out[ik] = cfma(a[i * 2 + 1], m[1 * 2 + k], t);
    }
}

__device__ __forceinline__ u64 pack2(float lo, float hi) {
    return (u64)__float_as_uint(lo) | ((u64)__float_as_uint(hi) << 32);
}
__device__ __forceinline__ void unpack2(u64 v, float& lo, float& hi) {
    lo = __uint_as_float((unsigned)v);
    hi = __uint_as_float((unsigned)(v >> 32));
}

// Rare fallback: recompute tile j's transform directly from inputs (bounded work).
__device__ void recompute_tile(const float* __restrict__ A, const float* __restrict__ X,
                               long jb, long step, Cplx TA[4], Cplx TX[4]) {
    load_mat_nt(A + jb, TA);
    load_mat_nt(X + jb, TX);
    for (int t = 1; t < TSPAN; ++t) {
        Cplx a[4], x[4], nA[4], nX[4];
        long p = jb + (long)t * step;
        load_mat_nt(A + p, a);
        load_mat_nt(X + p, x);
        matmul(a, TA, nA);
        matmul_add(a, TX, x, nX);
        #pragma unroll
        for (int k = 0; k < 4; ++k) { TA[k] = nA[k]; TX[k] = nX[k]; }
    }
}

__global__ __launch_bounds__(256, 2)
void pscan_persist(const float* __restrict__ A, const float* __restrict__ X,
                   unsigned char* __restrict__ wsb, float* __restrict__ out) {
    unsigned* counter = (unsigned*)wsb;
    unsigned* flags   = (unsigned*)(wsb + FLAG_OFF);
    u64* agg = (u64*)(wsb + CTRL_BYTES);
    u64* car = agg + (size_t)NT * AGG_U64_PER_TILE;

    const int tid = threadIdx.x;
    const int cl  = tid & (TCH - 1);   // channel within tile
    const int ss  = tid >> 5;          // sub-segment 0..7

    __shared__ unsigned s_ticket;
    __shared__ float2 smA[4][TSS][TCH];   // sub-segment transform totals (A part)
    __shared__ float2 smX[4][TSS][TCH];   // (X part); float2 layout -> 2-way LDS alias only

    const long step = (long)CC * 8;

    for (;;) {
        __syncthreads();                   // protect s_ticket + LDS from previous tile
        if (tid == 0) s_ticket = atomicAdd(counter, 1u);
        __syncthreads();
        const unsigned ticket = s_ticket;
        if (ticket >= (unsigned)NT) return;   // replay-safe: never indexes OOB

        const int pos   = ticket / NCHAIN;    // position-major tickets: preds earlier
        const int chain = ticket % NCHAIN;
        const int b  = chain / NCG;
        const int cg = chain % NCG;
        const int c  = cg * TCH + cl;

        const long base = (((long)b * LL + (long)pos * TSPAN + ss * SEG) * CC + c) * 8;

        // ---- phase 1: per-thread in-register inclusive scan over SEG timesteps
        Cplx Pa[SEG][4], Px[SEG][4];
        load_mat_nt(A + base, Pa[0]);
        load_mat_nt(X + base, Px[0]);
        #pragma unroll
        for (int t = 1; t < SEG; ++t) {
            Cplx a[4], x[4];
            long p = base + (long)t * step;
            load_mat_nt(A + p, a);
            load_mat_nt(X + p, x);
            matmul(a, Pa[t - 1], Pa[t]);
            matmul_add(a, Px[t - 1], x, Px[t]);
        }

        // ---- in-block scan across sub-segments (per channel)
        #pragma unroll
        for (int k = 0; k < 4; ++k) {
            smA[k][ss][cl] = make_float2(Pa[SEG - 1][k].r, Pa[SEG - 1][k].i);
            smX[k][ss][cl] = make_float2(Px[SEG - 1][k].r, Px[SEG - 1][k].i);
        }
        __syncthreads();

        // prefix of sub-segments below mine: P = T_{ss-1} o ... o T_0
        Cplx PAp[4], PXp[4];
        PAp[0] = {1.f, 0.f}; PAp[1] = {0.f, 0.f};
        PAp[2] = {0.f, 0.f}; PAp[3] = {1.f, 0.f};
        #pragma unroll
        for (int k = 0; k < 4; ++k) PXp[k] = {0.f, 0.f};
        for (int q = 0; q < ss; ++q) {
            Cplx Tq[4], Xq[4], nA[4], nX[4];
            #pragma unroll
            for (int k = 0; k < 4; ++k) {
                float2 va = smA[k][q][cl]; Tq[k].r = va.x; Tq[k].i = va.y;
                float2 vx = smX[k][q][cl]; Xq[k].r = vx.x; Xq[k].i = vx.y;
            }
            matmul(Tq, PAp, nA);             // P = T_q o P
            matmul_add(Tq, PXp, Xq, nX);
            #pragma unroll
            for (int k = 0; k < 4; ++k) { PAp[k] = nA[k]; PXp[k] = nX[k]; }
        }

        // tile total (only the last sub-segment's threads need it)
        Cplx TotA[4], TotX[4];
        if (ss == TSS - 1) {
            matmul(Pa[SEG - 1], PAp, TotA);
            matmul_add(Pa[SEG - 1], PXp, Px[SEG - 1], TotX);
        }

        const bool has_succ = (pos != NPOS - 1);

        // ---- publish aggregate BEFORE waiting (decoupled-lookback assist)
        if (has_succ) {
            if (ss == TSS - 1) {
                u64* am = agg + (size_t)ticket * AGG_U64_PER_TILE;
                #pragma unroll
                for (int k = 0; k < 4; ++k)
                    __hip_atomic_store(am + (size_t)k * TCH + cl, pack2(TotA[k].r, TotA[k].i),
                                       __ATOMIC_RELAXED, __HIP_MEMORY_SCOPE_AGENT);
                #pragma unroll
                for (int k = 0; k < 4; ++k)
                    __hip_atomic_store(am + (size_t)(4 + k) * TCH + cl, pack2(TotX[k].r, TotX[k].i),
                                       __ATOMIC_RELAXED, __HIP_MEMORY_SCOPE_AGENT);
            }
            __threadfence();
            __syncthreads();
            if (tid == 0)
                __hip_atomic_store(&flags[ticket], 1u, __ATOMIC_RELEASE, __HIP_MEMORY_SCOPE_AGENT);
        }

        // ---- obtain carry state Y entering this tile
        Cplx Yin[4];
        #pragma unroll
        for (int k = 0; k < 4; ++k) Yin[k] = {0.f, 0.f};

        if (pos > 0) {
            const int prev = (int)ticket - NCHAIN;
            unsigned f = 0;
            int polls = 0;
            do {
                f = __hip_atomic_load(&flags[prev], __ATOMIC_RELAXED, __HIP_MEMORY_SCOPE_AGENT);
                if (f == 2u) break;
                __builtin_amdgcn_s_sleep(2);
            } while (++polls < POLL_CAP);

            if (f == 2u) {
                __builtin_amdgcn_fence(__ATOMIC_ACQUIRE, "agent");
                const u64* cp = car + (size_t)prev * CAR_U64_PER_TILE;
                #pragma unroll
                for (int k = 0; k < 4; ++k) {
                    u64 v = __hip_atomic_load((u64*)cp + (size_t)k * TCH + cl,
                                              __ATOMIC_RELAXED, __HIP_MEMORY_SCOPE_AGENT);
                    unpack2(v, Yin[k].r, Yin[k].i);
                }
            } else {
                // slow path: walk backward folding aggregates; self-recompute if absent
                Cplx WA[4], WX[4];
                WA[0] = {1.f, 0.f}; WA[1] = {0.f, 0.f};
                WA[2] = {0.f, 0.f}; WA[3] = {1.f, 0.f};
                #pragma unroll
                for (int k = 0; k < 4; ++k) WX[k] = {0.f, 0.f};

                int j = prev;
                for (;;) {
                    unsigned fj = 0;
                    int p2 = 0;
                    do {
                        fj = __hip_atomic_load(&flags[j], __ATOMIC_RELAXED, __HIP_MEMORY_SCOPE_AGENT);
                        if (fj >= 1u) break;
                        __builtin_amdgcn_s_sleep(2);
                    } while (++p2 < POLL_CAP);

                    if (fj == 2u) {
                        __builtin_amdgcn_fence(__ATOMIC_ACQUIRE, "agent");
                        const u64* cp = car + (size_t)j * CAR_U64_PER_TILE;
                        Cplx Yj[4];
                        #pragma unroll
                        for (int k = 0; k < 4; ++k) {
                            u64 v = __hip_atomic_load((u64*)cp + (size_t)k * TCH + cl,
                                                      __ATOMIC_RELAXED, __HIP_MEMORY_SCOPE_AGENT);
                            unpack2(v, Yj[k].r, Yj[k].i);
                        }
                        matmul_add(WA, Yj, WX, Yin);     // Yin = W(Y_j)
                        break;
                    }

                    Cplx TA[4], TX[4];
                    if (fj == 1u) {
                        __builtin_amdgcn_fence(__ATOMIC_ACQUIRE, "agent");
                        const u64* am = agg + (size_t)j * AGG_U64_PER_TILE;
                        #pragma unroll
                        for (int k = 0; k < 4; ++k) {
                            u64 v = __hip_atomic_load((u64*)am + (size_t)k * TCH + cl,
                                                      __ATOMIC_RELAXED, __HIP_MEMORY_SCOPE_AGENT);
                            unpack2(v, TA[k].r, TA[k].i);
                        }
                        #pragma unroll
                        for (int k = 0; k < 4; ++k) {
                            u64 v = __hip_atomic_load((u64*)am + (size_t)(4 + k) * TCH + cl,
                                                      __ATOMIC_RELAXED, __HIP_MEMORY_SCOPE_AGENT);
                            unpack2(v, TX[k].r, TX[k].i);
                        }
                    } else {
                        int pj = j / NCHAIN;             // same chain as us
                        long jb = (((long)b * LL + (long)pj * TSPAN) * CC + c) * 8;
                        recompute_tile(A, X, jb, step, TA, TX);
                    }

                    Cplx nA[4], nX[4];                   // W = W o T_j
                    matmul(WA, TA, nA);
                    matmul_add(WA, TX, WX, nX);
                    #pragma unroll
                    for (int k = 0; k < 4; ++k) { WA[k] = nA[k]; WX[k] = nX[k]; }

                    if (j < NCHAIN) {                    // folded tile at pos 0: Y_{-1}=0
                        #pragma unroll
                        for (int k = 0; k < 4; ++k) Yin[k] = WX[k];
                        break;
                    }
                    j -= NCHAIN;
                }
            }
        }

        // ---- publish carry-out state ASAP (critical chain), before finalize
        if (has_succ) {
            if (ss == TSS - 1) {
                Cplx Yout[4];
                matmul_add(TotA, Yin, TotX, Yout);
                u64* cm = car + (size_t)ticket * CAR_U64_PER_TILE;
                #pragma unroll
                for (int k = 0; k < 4; ++k)
                    __hip_atomic_store(cm + (size_t)k * TCH + cl, pack2(Yout[k].r, Yout[k].i),
                                       __ATOMIC_RELAXED, __HIP_MEMORY_SCOPE_AGENT);
            }
            __threadfence();
            __syncthreads();
            if (tid == 0)
                __hip_atomic_store(&flags[ticket], 2u, __ATOMIC_RELEASE, __HIP_MEMORY_SCOPE_AGENT);
        }

        // ---- finalize from registers: Y0 = P(Yin); Y_t = Pa_t(Y0) + Px_t
        Cplx Y0[4];
        matmul_add(PAp, Yin, PXp, Y0);
        #pragma unroll
        for (int t = 0; t < SEG; ++t) {
            Cplx Y[4];
            matmul_add(Pa[t], Y0, Px[t], Y);
            store_mat_nt(out + base + (long)t * step, Y);
        }
    }
}

extern "C" void kernel_launch(void* const* d_in, const int* in_sizes, int n_in,
                              void* d_out, int out_size, void* d_ws, size_t ws_size,
                              hipStream_t stream) {
    const float* A = (const float*)d_in[0];
    const float* X = (const float*)d_in[1];

    // zero counter + flags (clears harness poison); payloads are flag-gated
    hipMemsetAsync(d_ws, 0, CTRL_BYTES, stream);
    pscan_persist<<<NBLK, dim3(256), 0, stream>>>(A, X, (unsigned char*)d_ws, (float*)d_out);
}